// Round 3
// baseline (389.753 us; speedup 1.0000x reference)
//
#include <hip/hip_runtime.h>

#define B_  64
#define K_  256
#define T_  64
#define DF_ 768
#define N_  1024

typedef __attribute__((ext_vector_type(8))) short bf16x8;
typedef __attribute__((ext_vector_type(4))) float f32x4;

__device__ __forceinline__ unsigned short bf_rne(float x) {
    unsigned u = __float_as_uint(x);
    unsigned r = u + 0x7fffu + ((u >> 16) & 1u);
    return (unsigned short)(r >> 16);
}

// ---------------------------------------------------------------------------
// prep_we: blocks [0,768): W[d][k] -> W_hi/W_lo [d][k], WT_hi [k][d]
//          blocks [768,1024): e[b][k][t] -> eT_hi/eT_lo [b][t][k]
// ---------------------------------------------------------------------------
__global__ __launch_bounds__(256) void prep_we(const float* __restrict__ W,
                                               const float* __restrict__ e,
                                               unsigned short* __restrict__ W_hi,
                                               unsigned short* __restrict__ W_lo,
                                               unsigned short* __restrict__ WT_hi,
                                               unsigned short* __restrict__ eT_hi,
                                               unsigned short* __restrict__ eT_lo) {
    int blk = blockIdx.x;
    if (blk < DF_) {
        int d = blk, k = threadIdx.x;
        float w = W[d * K_ + k];
        unsigned u = __float_as_uint(w);
        unsigned short hs = (unsigned short)(u >> 16);  // truncation: exact hi
        float hi = __uint_as_float(u & 0xffff0000u);
        W_hi[d * K_ + k]   = hs;
        W_lo[d * K_ + k]   = bf_rne(w - hi);
        WT_hi[k * DF_ + d] = hs;
    } else {
        int q = blk - DF_;            // [0,256)
        int b = q >> 2, kq = q & 3;
        int t = threadIdx.x & 63, ko = threadIdx.x >> 6;
        const float* eb = e + (size_t)b * K_ * T_;
        unsigned short* eh = eT_hi + (size_t)b * T_ * K_;
        unsigned short* el = eT_lo + (size_t)b * T_ * K_;
#pragma unroll
        for (int i = 0; i < 16; i++) {
            int k = kq * 64 + ko * 16 + i;
            float x = eb[k * T_ + t];            // coalesced over t
            unsigned u = __float_as_uint(x);
            unsigned short hs = (unsigned short)(u >> 16);
            float hi = __uint_as_float(u & 0xffff0000u);
            eh[t * K_ + k] = hs;
            el[t * K_ + k] = bf_rne(x - hi);
        }
    }
}

// ---------------------------------------------------------------------------
// gemm_g: gT[t][d] = sum_k e[k][t]*W[d][k]   (split-bf16, 3-pass MFMA)
// grid (DF/64, B) = 768 blocks, tile [64t x 64d], BK=32.
// One-barrier double-buffered; (256,3) -> all 768 blocks resident.
// ---------------------------------------------------------------------------
__global__ __launch_bounds__(256, 3) void gemm_g(const unsigned short* __restrict__ eT_hi,
                                                 const unsigned short* __restrict__ eT_lo,
                                                 const unsigned short* __restrict__ W_hi,
                                                 const unsigned short* __restrict__ W_lo,
                                                 unsigned short* __restrict__ gT_hi,
                                                 unsigned short* __restrict__ gT_lo) {
    __shared__ unsigned short LeH[2][64 * 40], LeL[2][64 * 40];
    __shared__ unsigned short LwH[2][64 * 40], LwL[2][64 * 40];
    const int dblk = blockIdx.x * 64;
    const int b = blockIdx.y;
    const int tid = threadIdx.x;
    const int lane = tid & 63, w = tid >> 6, q = lane >> 4, l16 = lane & 15;

    const unsigned short* eh = eT_hi + (size_t)b * T_ * K_;
    const unsigned short* el = eT_lo + (size_t)b * T_ * K_;

    f32x4 acc[4];
#pragma unroll
    for (int i = 0; i < 4; i++) acc[i] = (f32x4)(0.f);

    const int tr = tid >> 2, c8 = (tid & 3) * 8;
    const unsigned short* ehp = eh + (size_t)tr * K_ + c8;
    const unsigned short* elp = el + (size_t)tr * K_ + c8;
    const unsigned short* whp = W_hi + (size_t)(dblk + tr) * K_ + c8;
    const unsigned short* wlp = W_lo + (size_t)(dblk + tr) * K_ + c8;

    uint4 peH, peL, pwH, pwL;
    auto gload = [&](int k0) {
        peH = *(const uint4*)&ehp[k0];
        peL = *(const uint4*)&elp[k0];
        pwH = *(const uint4*)&whp[k0];
        pwL = *(const uint4*)&wlp[k0];
    };
    auto gstore = [&](int buf) {
        *(uint4*)&LeH[buf][tr * 40 + c8] = peH;
        *(uint4*)&LeL[buf][tr * 40 + c8] = peL;
        *(uint4*)&LwH[buf][tr * 40 + c8] = pwH;
        *(uint4*)&LwL[buf][tr * 40 + c8] = pwL;
    };
    auto gcomp = [&](int buf) {
        bf16x8 aH[4], aL[4], bH, bL;
#pragma unroll
        for (int mt = 0; mt < 4; mt++) {
            aH[mt] = *(const bf16x8*)&LeH[buf][(mt * 16 + l16) * 40 + q * 8];
            aL[mt] = *(const bf16x8*)&LeL[buf][(mt * 16 + l16) * 40 + q * 8];
        }
        int dl = w * 16 + l16;
        bH = *(const bf16x8*)&LwH[buf][dl * 40 + q * 8];
        bL = *(const bf16x8*)&LwL[buf][dl * 40 + q * 8];
#pragma unroll
        for (int mt = 0; mt < 4; mt++) {
            acc[mt] = __builtin_amdgcn_mfma_f32_16x16x32_bf16(aH[mt], bH, acc[mt], 0, 0, 0);
            acc[mt] = __builtin_amdgcn_mfma_f32_16x16x32_bf16(aH[mt], bL, acc[mt], 0, 0, 0);
            acc[mt] = __builtin_amdgcn_mfma_f32_16x16x32_bf16(aL[mt], bH, acc[mt], 0, 0, 0);
        }
    };

    gload(0);
    gstore(0);
    __syncthreads();
    int cur = 0;
    for (int k0 = 0; k0 < K_ - 32; k0 += 32) {
        gload(k0 + 32);
        gcomp(cur);
        gstore(cur ^ 1);
        __syncthreads();
        cur ^= 1;
    }
    gcomp(cur);

    unsigned short* gh = gT_hi + (size_t)b * T_ * DF_;
    unsigned short* gl = gT_lo + (size_t)b * T_ * DF_;
#pragma unroll
    for (int mt = 0; mt < 4; mt++)
#pragma unroll
        for (int r = 0; r < 4; r++) {
            float x = acc[mt][r];
            int t = mt * 16 + q * 4 + r;
            int d = dblk + w * 16 + l16;
            unsigned u = __float_as_uint(x);
            unsigned short hs = (unsigned short)(u >> 16);
            float hi = __uint_as_float(u & 0xffff0000u);
            gh[t * DF_ + d] = hs;
            gl[t * DF_ + d] = bf_rne(x - hi);
        }
}

// ---------------------------------------------------------------------------
// gemm_s: s[t][n] = sum_d g[d][t]*f[d][n]   (split-bf16, 3-pass)
// 512 blocks (XCD-swizzled: all 8 n-tiles of a b on one XCD -> gT L2-hot),
// tile [64t x 128n], BK=32, 2 blocks/CU.
// f staged in dbuf LDS (one barrier/iter); g A-fragments read DIRECTLY from
// global (L2) into registers, prefetched one iter ahead -- the barrier's
// vmcnt drain guarantees arrival, so next iter's MFMAs never stall on them.
// ---------------------------------------------------------------------------
__global__ __launch_bounds__(256, 2) void gemm_s(const unsigned short* __restrict__ gT_hi,
                                                 const unsigned short* __restrict__ gT_lo,
                                                 const float* __restrict__ f,
                                                 float* __restrict__ s) {
    __shared__ unsigned LfH[2][128 * 20], LfL[2][128 * 20];   // u32 = packed bf16 (d,d+1)

    const int flat = blockIdx.x;                  // 512 blocks
    const int b    = (flat & 7) * 8 + ((flat >> 3) & 7);
    const int nblk = (flat >> 6) * 128;
    const int tid = threadIdx.x;
    const int lane = tid & 63, w = tid >> 6, q = lane >> 4, l16 = lane & 15;

    const unsigned short* gh = gT_hi + (size_t)b * T_ * DF_;
    const unsigned short* gl = gT_lo + (size_t)b * T_ * DF_;

    f32x4 acc[4][2];
#pragma unroll
    for (int i = 0; i < 4; i++)
#pragma unroll
        for (int j = 0; j < 2; j++) acc[i][j] = (f32x4)(0.f);

    const int dp  = tid >> 4;          // d-pair 0..15
    const int nb  = (tid & 15) * 8;    // 8 consecutive n per thread
    const int rot = tid & 7;

    const float* fbase = f + ((size_t)b * DF_ + dp * 2) * N_ + nblk + nb;
    // per-lane A-fragment base: row (mt*16+l16), col q*8  (16B aligned)
    const unsigned short* gfh = gh + (size_t)l16 * DF_ + q * 8;
    const unsigned short* gfl = gl + (size_t)l16 * DF_ + q * 8;

    float4 px0, px1, py0, py1;
    auto sload = [&](int d0) {
        const float* fp = fbase + (size_t)d0 * N_;
        px0 = *(const float4*)&fp[0];
        px1 = *(const float4*)&fp[4];
        py0 = *(const float4*)&fp[N_ + 0];
        py1 = *(const float4*)&fp[N_ + 4];
    };
    auto sstore = [&](int buf) {
        const float xs[8] = {px0.x, px0.y, px0.z, px0.w, px1.x, px1.y, px1.z, px1.w};
        const float ys[8] = {py0.x, py0.y, py0.z, py0.w, py1.x, py1.y, py1.z, py1.w};
#pragma unroll
        for (int jj = 0; jj < 8; jj++) {
            int j = (jj + rot) & 7;            // lane-rotated: kills bank conflicts
            unsigned bx = __float_as_uint(xs[j]);
            unsigned by = __float_as_uint(ys[j]);
            unsigned hp = (bx >> 16) | (by & 0xffff0000u);
            float lx = xs[j] - __uint_as_float(bx & 0xffff0000u);
            float ly = ys[j] - __uint_as_float(by & 0xffff0000u);
            unsigned lp = (__float_as_uint(lx) >> 16) | (__float_as_uint(ly) & 0xffff0000u);
            LfH[buf][(nb + j) * 20 + dp] = hp;
            LfL[buf][(nb + j) * 20 + dp] = lp;
        }
    };
    auto gfrag = [&](bf16x8 (&H)[4], bf16x8 (&L)[4], int d0) {
#pragma unroll
        for (int mt = 0; mt < 4; mt++) {
            H[mt] = *(const bf16x8*)&gfh[(size_t)(mt * 16) * DF_ + d0];
            L[mt] = *(const bf16x8*)&gfl[(size_t)(mt * 16) * DF_ + d0];
        }
    };
    auto scomp = [&](int buf, const bf16x8 (&aH)[4], const bf16x8 (&aL)[4]) {
        bf16x8 bH[2], bL[2];
#pragma unroll
        for (int nt = 0; nt < 2; nt++) {
            int nl = w * 32 + nt * 16 + l16;
            bH[nt] = *(const bf16x8*)&((const unsigned short*)LfH[buf])[nl * 40 + q * 8];
            bL[nt] = *(const bf16x8*)&((const unsigned short*)LfL[buf])[nl * 40 + q * 8];
        }
#pragma unroll
        for (int mt = 0; mt < 4; mt++)
#pragma unroll
            for (int nt = 0; nt < 2; nt++) {
                acc[mt][nt] = __builtin_amdgcn_mfma_f32_16x16x32_bf16(aH[mt], bH[nt], acc[mt][nt], 0, 0, 0);
                acc[mt][nt] = __builtin_amdgcn_mfma_f32_16x16x32_bf16(aH[mt], bL[nt], acc[mt][nt], 0, 0, 0);
                acc[mt][nt] = __builtin_amdgcn_mfma_f32_16x16x32_bf16(aL[mt], bH[nt], acc[mt][nt], 0, 0, 0);
            }
    };

    bf16x8 aH[4], aL[4], nH[4], nL[4];
    sload(0);
    gfrag(aH, aL, 0);
    sstore(0);
    __syncthreads();
    int cur = 0;
    for (int d0 = 0; d0 < DF_ - 32; d0 += 32) {
        sload(d0 + 32);            // next f tile -> regs
        gfrag(nH, nL, d0 + 32);    // next g frags -> regs (done by barrier)
        scomp(cur, aH, aL);        // MFMA on current
        sstore(cur ^ 1);           // consume f loads after MFMAs
        __syncthreads();
#pragma unroll
        for (int i = 0; i < 4; i++) { aH[i] = nH[i]; aL[i] = nL[i]; }
        cur ^= 1;
    }
    scomp(cur, aH, aL);

    float* sb = s + (size_t)b * T_ * N_;
#pragma unroll
    for (int mt = 0; mt < 4; mt++)
#pragma unroll
        for (int nt = 0; nt < 2; nt++)
#pragma unroll
            for (int r = 0; r < 4; r++) {
                int t = mt * 16 + q * 4 + r;
                int n = nblk + w * 32 + nt * 16 + l16;
                sb[(size_t)t * N_ + n] = acc[mt][nt][r];
            }
}

// ---------------------------------------------------------------------------
// softmax over n -> bf16 alpha.  One wave per row: no LDS, no barriers.
// ---------------------------------------------------------------------------
__global__ __launch_bounds__(256) void softmax_k(const float* __restrict__ s,
                                                 unsigned short* __restrict__ alpha,
                                                 const float* __restrict__ gptr) {
    const float g = gptr[0];
    const int row_id = blockIdx.x * 4 + (threadIdx.x >> 6);
    const int lane = threadIdx.x & 63;
    const float* row = s + (size_t)row_id * N_;
    unsigned short* arow = alpha + (size_t)row_id * N_;

    float4 x[4];
#pragma unroll
    for (int i = 0; i < 4; i++) {
        x[i] = *(const float4*)(row + i * 256 + lane * 4);   // perfectly coalesced
        x[i].x *= g; x[i].y *= g; x[i].z *= g; x[i].w *= g;
    }
    float m = x[0].x;
#pragma unroll
    for (int i = 0; i < 4; i++)
        m = fmaxf(m, fmaxf(fmaxf(x[i].x, x[i].y), fmaxf(x[i].z, x[i].w)));
#pragma unroll
    for (int off = 32; off > 0; off >>= 1) m = fmaxf(m, __shfl_xor(m, off, 64));

    float ev[16];
    float sum = 0.f;
#pragma unroll
    for (int i = 0; i < 4; i++) {
        ev[i * 4 + 0] = __expf(x[i].x - m);
        ev[i * 4 + 1] = __expf(x[i].y - m);
        ev[i * 4 + 2] = __expf(x[i].z - m);
        ev[i * 4 + 3] = __expf(x[i].w - m);
        sum += ev[i * 4 + 0] + ev[i * 4 + 1] + ev[i * 4 + 2] + ev[i * 4 + 3];
    }
#pragma unroll
    for (int off = 32; off > 0; off >>= 1) sum += __shfl_xor(sum, off, 64);
    float inv = 1.f / sum;
#pragma unroll
    for (int i = 0; i < 4; i++) {
        unsigned p0 = (unsigned)bf_rne(ev[i * 4 + 0] * inv) | ((unsigned)bf_rne(ev[i * 4 + 1] * inv) << 16);
        unsigned p1 = (unsigned)bf_rne(ev[i * 4 + 2] * inv) | ((unsigned)bf_rne(ev[i * 4 + 3] * inv) << 16);
        uint2 o; o.x = p0; o.y = p1;
        *(uint2*)&arow[i * 256 + lane * 4] = o;
    }
}

// ---------------------------------------------------------------------------
// gemm_h: hT[t][d] = sum_n f[d][n]*alpha[t][n]   (plain bf16)
// grid (DF/64, B) = 768 blocks, tile [64d x 64t], BK=64.
// Dbuf one-barrier; (256,3) -> all 768 blocks resident.
// ---------------------------------------------------------------------------
__global__ __launch_bounds__(256, 3) void gemm_h(const float* __restrict__ f,
                                                 const unsigned short* __restrict__ alpha,
                                                 unsigned short* __restrict__ hT) {
    __shared__ unsigned short Lf[2][64 * 72];
    __shared__ unsigned short La[2][64 * 72];
    const int dblk = blockIdx.x * 64;
    const int b = blockIdx.y;
    const int tid = threadIdx.x;
    const int lane = tid & 63, w = tid >> 6, q = lane >> 4, l16 = lane & 15;

    const float* fb = f + (size_t)b * DF_ * N_;
    const unsigned short* ab = alpha + (size_t)b * T_ * N_;

    f32x4 acc[4];
#pragma unroll
    for (int i = 0; i < 4; i++) acc[i] = (f32x4)(0.f);

    const int fr_ = tid >> 2, fc = tid & 3;
    const float* frbase = fb + (size_t)(dblk + fr_) * N_ + fc * 16;
    const unsigned short* abase = ab + (size_t)fr_ * N_ + fc * 16;

    float4 pf0, pf1, pf2, pf3;
    uint4 pa0, pa1;

    auto hload = [&](int n0) {
        const float* fp = frbase + n0;
        pf0 = *(const float4*)&fp[0];
        pf1 = *(const float4*)&fp[4];
        pf2 = *(const float4*)&fp[8];
        pf3 = *(const float4*)&fp[12];
        pa0 = *(const uint4*)&abase[n0];
        pa1 = *(const uint4*)&abase[n0 + 8];
    };
    auto hstore = [&](int buf) {
        const float4 fx[4] = {pf0, pf1, pf2, pf3};
#pragma unroll
        for (int i = 0; i < 4; i++) {
            float4 x = fx[i];
            unsigned p0 = (unsigned)bf_rne(x.x) | ((unsigned)bf_rne(x.y) << 16);
            unsigned p1 = (unsigned)bf_rne(x.z) | ((unsigned)bf_rne(x.w) << 16);
            uint2 o; o.x = p0; o.y = p1;
            *(uint2*)&Lf[buf][fr_ * 72 + fc * 16 + i * 4] = o;
        }
        *(uint4*)&La[buf][fr_ * 72 + fc * 16]     = pa0;
        *(uint4*)&La[buf][fr_ * 72 + fc * 16 + 8] = pa1;
    };
    auto hcomp = [&](int buf) {
        bf16x8 af[2], bb[4][2];
#pragma unroll
        for (int kk = 0; kk < 2; kk++)
            af[kk] = *(const bf16x8*)&Lf[buf][(w * 16 + l16) * 72 + kk * 32 + q * 8];
#pragma unroll
        for (int nt = 0; nt < 4; nt++)
#pragma unroll
            for (int kk = 0; kk < 2; kk++)
                bb[nt][kk] = *(const bf16x8*)&La[buf][(nt * 16 + l16) * 72 + kk * 32 + q * 8];
#pragma unroll
        for (int nt = 0; nt < 4; nt++)
#pragma unroll
            for (int kk = 0; kk < 2; kk++)
                acc[nt] = __builtin_amdgcn_mfma_f32_16x16x32_bf16(af[kk], bb[nt][kk], acc[nt], 0, 0, 0);
    };

    hload(0);
    hstore(0);
    __syncthreads();
    int cur = 0;
    for (int n0 = 0; n0 < N_ - 64; n0 += 64) {
        hload(n0 + 64);        // issue next-tile loads
        hcomp(cur);            // compute current buffer
        hstore(cur ^ 1);       // consume loads after MFMAs
        __syncthreads();
        cur ^= 1;
    }
    hcomp(cur);

    unsigned short* hb = hT + (size_t)b * T_ * DF_;
#pragma unroll
    for (int nt = 0; nt < 4; nt++)
#pragma unroll
        for (int r = 0; r < 4; r++) {
            int d = dblk + w * 16 + q * 4 + r;
            int t = nt * 16 + l16;
            hb[(size_t)t * DF_ + d] = bf_rne(acc[nt][r]);
        }
}

// ---------------------------------------------------------------------------
// gemm_c: c[k][t] = sum_d W[d][k]*h[d][t] + bias[k]   (plain bf16)
// grid (K/64, B) = 256 blocks (1 block/CU), tile [64k x 64t], BK=64.
// Dbuf one-barrier: with 1 block/CU the pipeline is the only latency hiding.
// ---------------------------------------------------------------------------
__global__ __launch_bounds__(256, 2) void gemm_c(const unsigned short* __restrict__ WT_hi,
                                                 const unsigned short* __restrict__ hT,
                                                 const float* __restrict__ bias,
                                                 float* __restrict__ c) {
    __shared__ unsigned short LW[2][64 * 72];
    __shared__ unsigned short Lh[2][64 * 72];
    const int kblk = blockIdx.x * 64;
    const int b = blockIdx.y;
    const int tid = threadIdx.x;
    const int lane = tid & 63, w = tid >> 6, q = lane >> 4, l16 = lane & 15;

    const unsigned short* hb = hT + (size_t)b * T_ * DF_;

    f32x4 acc[4];
#pragma unroll
    for (int i = 0; i < 4; i++) acc[i] = (f32x4)(0.f);

    const int r_ = tid >> 2, cc = (tid & 3) * 16;
    const unsigned short* wbase = WT_hi + (size_t)(kblk + r_) * DF_ + cc;
    const unsigned short* hbase = hb + (size_t)r_ * DF_ + cc;

    uint4 pw0, pw1, ph0, ph1;
    auto cload = [&](int d0) {
        pw0 = *(const uint4*)&wbase[d0];
        pw1 = *(const uint4*)&wbase[d0 + 8];
        ph0 = *(const uint4*)&hbase[d0];
        ph1 = *(const uint4*)&hbase[d0 + 8];
    };
    auto cstore = [&](int buf) {
        *(uint4*)&LW[buf][r_ * 72 + cc]     = pw0;
        *(uint4*)&LW[buf][r_ * 72 + cc + 8] = pw1;
        *(uint4*)&Lh[buf][r_ * 72 + cc]     = ph0;
        *(uint4*)&Lh[buf][r_ * 72 + cc + 8] = ph1;
    };
    auto ccomp = [&](int buf) {
        bf16x8 aw[2], bh[4][2];
#pragma unroll
        for (int kk = 0; kk < 2; kk++)
            aw[kk] = *(const bf16x8*)&LW[buf][(w * 16 + l16) * 72 + kk * 32 + q * 8];
#pragma unroll
        for (int nt = 0; nt < 4; nt++)
#pragma unroll
            for (int kk = 0; kk < 2; kk++)
                bh[nt][kk] = *(const bf16x8*)&Lh[buf][(nt * 16 + l16) * 72 + kk * 32 + q * 8];
#pragma unroll
        for (int nt = 0; nt < 4; nt++)
#pragma unroll
            for (int kk = 0; kk < 2; kk++)
                acc[nt] = __builtin_amdgcn_mfma_f32_16x16x32_bf16(aw[kk], bh[nt][kk], acc[nt], 0, 0, 0);
    };

    cload(0);
    cstore(0);
    __syncthreads();
    int cur = 0;
    for (int d0 = 0; d0 < DF_ - 64; d0 += 64) {
        cload(d0 + 64);
        ccomp(cur);
        cstore(cur ^ 1);
        __syncthreads();
        cur ^= 1;
    }
    ccomp(cur);

    float* cb = c + (size_t)b * K_ * T_;
#pragma unroll
    for (int nt = 0; nt < 4; nt++)
#pragma unroll
        for (int r = 0; r < 4; r++) {
            int k = kblk + w * 16 + q * 4 + r;
            int t = nt * 16 + l16;
            cb[(size_t)k * T_ + t] = acc[nt][r] + bias[k];
        }
}

// ---------------------------------------------------------------------------
// cos_k: cos[b,i,j] = <c[:,i], e[:,j]> / (|c[:,i]| |e[:,j]|)
// ---------------------------------------------------------------------------
__global__ __launch_bounds__(256) void cos_k(const float* __restrict__ c,
                                             const float* __restrict__ e,
                                             float* __restrict__ out) {
    const int iq = threadIdx.x >> 6;
    const int i = blockIdx.x * 4 + iq;
    const int b = blockIdx.y;
    const int j = threadIdx.x & 63;
    const float* cb = c + (size_t)b * K_ * T_;
    const float* eb = e + (size_t)b * K_ * T_;

    float dot = 0.f, se = 0.f, sc = 0.f;
#pragma unroll 8
    for (int k = 0; k < K_; k++) {
        float cv = cb[(size_t)k * T_ + i];
        float ev = eb[(size_t)k * T_ + j];
        dot += cv * ev;
        se  += ev * ev;
        sc  += cv * cv;
    }
    out[((size_t)b * T_ + i) * T_ + j] = dot * rsqrtf(sc * se);
}

// ---------------------------------------------------------------------------
extern "C" void kernel_launch(void* const* d_in, const int* in_sizes, int n_in,
                              void* d_out, int out_size, void* d_ws, size_t ws_size,
                              hipStream_t stream) {
    const float* e     = (const float*)d_in[0];  // [B,K,T]
    const float* f     = (const float*)d_in[1];  // [B,DF,N]
    const float* gamma = (const float*)d_in[2];
    const float* W     = (const float*)d_in[3];  // [DF,K]
    const float* bias  = (const float*)d_in[4];  // [K]
    float* out = (float*)d_out;                  // [B,T,T]

    char* p = (char*)d_ws;
    unsigned short* W_hi  = (unsigned short*)p; p += (size_t)DF_ * K_ * 2;
    unsigned short* W_lo  = (unsigned short*)p; p += (size_t)DF_ * K_ * 2;
    unsigned short* WT_hi = (unsigned short*)p; p += (size_t)DF_ * K_ * 2;
    unsigned short* eT_hi = (unsigned short*)p; p += (size_t)B_ * T_ * K_ * 2;
    unsigned short* eT_lo = (unsigned short*)p; p += (size_t)B_ * T_ * K_ * 2;
    unsigned short* gT_hi = (unsigned short*)p; p += (size_t)B_ * T_ * DF_ * 2;
    unsigned short* gT_lo = (unsigned short*)p; p += (size_t)B_ * T_ * DF_ * 2;
    float*          s     = (float*)p;          p += (size_t)B_ * T_ * N_ * 4;
    unsigned short* alpha = (unsigned short*)p; p += (size_t)B_ * T_ * N_ * 2;
    unsigned short* hT    = (unsigned short*)p; p += (size_t)B_ * T_ * DF_ * 2;
    float*          c     = (float*)p;          p += (size_t)B_ * K_ * T_ * 4;

    prep_we <<<dim3(DF_ + 256),      256, 0, stream>>>(W, e, W_hi, W_lo, WT_hi, eT_hi, eT_lo);
    gemm_g  <<<dim3(DF_ / 64, B_),   256, 0, stream>>>(eT_hi, eT_lo, W_hi, W_lo, gT_hi, gT_lo);
    gemm_s  <<<dim3(512),            256, 0, stream>>>(gT_hi, gT_lo, f, s);
    softmax_k<<<dim3(B_ * T_ / 4),   256, 0, stream>>>(s, alpha, gamma);
    gemm_h  <<<dim3(DF_ / 64, B_),   256, 0, stream>>>(f, alpha, hT);
    gemm_c  <<<dim3(K_ / 64, B_),    256, 0, stream>>>(WT_hi, hT, bias, c);
    cos_k   <<<dim3(T_ / 4, B_),     256, 0, stream>>>(c, e, out);
}

// Round 5
// 377.143 us; speedup vs baseline: 1.0334x; 1.0334x over previous
//
#include <hip/hip_runtime.h>

#define B_  64
#define K_  256
#define T_  64
#define DF_ 768
#define N_  1024

typedef __attribute__((ext_vector_type(8))) short bf16x8;
typedef __attribute__((ext_vector_type(4))) float f32x4;

__device__ __forceinline__ unsigned short bf_rne(float x) {
    unsigned u = __float_as_uint(x);
    unsigned r = u + 0x7fffu + ((u >> 16) & 1u);
    return (unsigned short)(r >> 16);
}

// ---------------------------------------------------------------------------
// prep_we: blocks [0,768): W[d][k] -> W_hi/W_lo [d][k], WT_hi [k][d]
//          blocks [768,1024): e[b][k][t] -> eT_hi/eT_lo [b][t][k]
// ---------------------------------------------------------------------------
__global__ __launch_bounds__(256) void prep_we(const float* __restrict__ W,
                                               const float* __restrict__ e,
                                               unsigned short* __restrict__ W_hi,
                                               unsigned short* __restrict__ W_lo,
                                               unsigned short* __restrict__ WT_hi,
                                               unsigned short* __restrict__ eT_hi,
                                               unsigned short* __restrict__ eT_lo) {
    int blk = blockIdx.x;
    if (blk < DF_) {
        int d = blk, k = threadIdx.x;
        float w = W[d * K_ + k];
        unsigned u = __float_as_uint(w);
        unsigned short hs = (unsigned short)(u >> 16);  // truncation: exact hi
        float hi = __uint_as_float(u & 0xffff0000u);
        W_hi[d * K_ + k]   = hs;
        W_lo[d * K_ + k]   = bf_rne(w - hi);
        WT_hi[k * DF_ + d] = hs;
    } else {
        int q = blk - DF_;            // [0,256)
        int b = q >> 2, kq = q & 3;
        int t = threadIdx.x & 63, ko = threadIdx.x >> 6;
        const float* eb = e + (size_t)b * K_ * T_;
        unsigned short* eh = eT_hi + (size_t)b * T_ * K_;
        unsigned short* el = eT_lo + (size_t)b * T_ * K_;
#pragma unroll
        for (int i = 0; i < 16; i++) {
            int k = kq * 64 + ko * 16 + i;
            float x = eb[k * T_ + t];            // coalesced over t
            unsigned u = __float_as_uint(x);
            unsigned short hs = (unsigned short)(u >> 16);
            float hi = __uint_as_float(u & 0xffff0000u);
            eh[t * K_ + k] = hs;
            el[t * K_ + k] = bf_rne(x - hi);
        }
    }
}

// ---------------------------------------------------------------------------
// gemm_g: gT[t][d] = sum_k e[k][t]*W[d][k]   (split-bf16, 3-pass MFMA)
// grid (DF/64, B) = 768 blocks, tile [64t x 64d], BK=32.
// One-barrier double-buffered (round-2-validated scheme), (256,2).
// ---------------------------------------------------------------------------
__global__ __launch_bounds__(256, 2) void gemm_g(const unsigned short* __restrict__ eT_hi,
                                                 const unsigned short* __restrict__ eT_lo,
                                                 const unsigned short* __restrict__ W_hi,
                                                 const unsigned short* __restrict__ W_lo,
                                                 unsigned short* __restrict__ gT_hi,
                                                 unsigned short* __restrict__ gT_lo) {
    __shared__ unsigned short LeH[2][64 * 40], LeL[2][64 * 40];
    __shared__ unsigned short LwH[2][64 * 40], LwL[2][64 * 40];
    const int dblk = blockIdx.x * 64;
    const int b = blockIdx.y;
    const int tid = threadIdx.x;
    const int lane = tid & 63, w = tid >> 6, q = lane >> 4, l16 = lane & 15;

    const unsigned short* eh = eT_hi + (size_t)b * T_ * K_;
    const unsigned short* el = eT_lo + (size_t)b * T_ * K_;

    f32x4 acc[4];
#pragma unroll
    for (int i = 0; i < 4; i++) acc[i] = (f32x4)(0.f);

    const int tr = tid >> 2, c8 = (tid & 3) * 8;
    const unsigned short* ehp = eh + (size_t)tr * K_ + c8;
    const unsigned short* elp = el + (size_t)tr * K_ + c8;
    const unsigned short* whp = W_hi + (size_t)(dblk + tr) * K_ + c8;
    const unsigned short* wlp = W_lo + (size_t)(dblk + tr) * K_ + c8;

    uint4 peH, peL, pwH, pwL;
    auto gload = [&](int k0) {
        peH = *(const uint4*)&ehp[k0];
        peL = *(const uint4*)&elp[k0];
        pwH = *(const uint4*)&whp[k0];
        pwL = *(const uint4*)&wlp[k0];
    };
    auto gstore = [&](int buf) {
        *(uint4*)&LeH[buf][tr * 40 + c8] = peH;
        *(uint4*)&LeL[buf][tr * 40 + c8] = peL;
        *(uint4*)&LwH[buf][tr * 40 + c8] = pwH;
        *(uint4*)&LwL[buf][tr * 40 + c8] = pwL;
    };
    auto gcomp = [&](int buf) {
        bf16x8 aH[4], aL[4], bH, bL;
#pragma unroll
        for (int mt = 0; mt < 4; mt++) {
            aH[mt] = *(const bf16x8*)&LeH[buf][(mt * 16 + l16) * 40 + q * 8];
            aL[mt] = *(const bf16x8*)&LeL[buf][(mt * 16 + l16) * 40 + q * 8];
        }
        int dl = w * 16 + l16;
        bH = *(const bf16x8*)&LwH[buf][dl * 40 + q * 8];
        bL = *(const bf16x8*)&LwL[buf][dl * 40 + q * 8];
#pragma unroll
        for (int mt = 0; mt < 4; mt++) {
            acc[mt] = __builtin_amdgcn_mfma_f32_16x16x32_bf16(aH[mt], bH, acc[mt], 0, 0, 0);
            acc[mt] = __builtin_amdgcn_mfma_f32_16x16x32_bf16(aH[mt], bL, acc[mt], 0, 0, 0);
            acc[mt] = __builtin_amdgcn_mfma_f32_16x16x32_bf16(aL[mt], bH, acc[mt], 0, 0, 0);
        }
    };

    gload(0);
    gstore(0);
    __syncthreads();
    int cur = 0;
    for (int k0 = 0; k0 < K_ - 32; k0 += 32) {
        gload(k0 + 32);
        gcomp(cur);
        gstore(cur ^ 1);
        __syncthreads();
        cur ^= 1;
    }
    gcomp(cur);

    unsigned short* gh = gT_hi + (size_t)b * T_ * DF_;
    unsigned short* gl = gT_lo + (size_t)b * T_ * DF_;
#pragma unroll
    for (int mt = 0; mt < 4; mt++)
#pragma unroll
        for (int r = 0; r < 4; r++) {
            float x = acc[mt][r];
            int t = mt * 16 + q * 4 + r;
            int d = dblk + w * 16 + l16;
            unsigned u = __float_as_uint(x);
            unsigned short hs = (unsigned short)(u >> 16);
            float hi = __uint_as_float(u & 0xffff0000u);
            gh[t * DF_ + d] = hs;
            gl[t * DF_ + d] = bf_rne(x - hi);
        }
}

// ---------------------------------------------------------------------------
// gemm_s: s[t][n] = sum_d g[d][t]*f[d][n]   (split-bf16, 3-pass)
// 512 blocks (XCD-swizzled), tile [64t x 128n], BK=32, 2 blocks/CU.
// Round-2 form: g staged in dbuf LDS via coalesced loads (the direct-global
// fragment variant of round 3 was 16-lane x 1536B-stride uncoalesced -> revert).
// ---------------------------------------------------------------------------
__global__ __launch_bounds__(256, 2) void gemm_s(const unsigned short* __restrict__ gT_hi,
                                                 const unsigned short* __restrict__ gT_lo,
                                                 const float* __restrict__ f,
                                                 float* __restrict__ s) {
    __shared__ unsigned short LgH[2][64 * 40], LgL[2][64 * 40];
    __shared__ unsigned LfH[2][128 * 20], LfL[2][128 * 20];   // u32 = packed bf16 (d,d+1)

    const int flat = blockIdx.x;                  // 512 blocks
    const int b    = (flat & 7) * 8 + ((flat >> 3) & 7);
    const int nblk = (flat >> 6) * 128;
    const int tid = threadIdx.x;
    const int lane = tid & 63, w = tid >> 6, q = lane >> 4, l16 = lane & 15;

    const unsigned short* gh = gT_hi + (size_t)b * T_ * DF_;
    const unsigned short* gl = gT_lo + (size_t)b * T_ * DF_;

    f32x4 acc[4][2];
#pragma unroll
    for (int i = 0; i < 4; i++)
#pragma unroll
        for (int j = 0; j < 2; j++) acc[i][j] = (f32x4)(0.f);

    const int dp  = tid >> 4;          // d-pair 0..15
    const int nb  = (tid & 15) * 8;    // 8 consecutive n per thread
    const int rot = tid & 7;
    const int tr = tid >> 2, c8 = (tid & 3) * 8;

    const float* fbase = f + ((size_t)b * DF_ + dp * 2) * N_ + nblk + nb;
    const unsigned short* ghp = gh + (size_t)tr * DF_ + c8;
    const unsigned short* glp = gl + (size_t)tr * DF_ + c8;

    float4 px0, px1, py0, py1;
    uint4 pgH, pgL;

    auto sload = [&](int d0) {
        const float* fp = fbase + (size_t)d0 * N_;
        px0 = *(const float4*)&fp[0];
        px1 = *(const float4*)&fp[4];
        py0 = *(const float4*)&fp[N_ + 0];
        py1 = *(const float4*)&fp[N_ + 4];
        pgH = *(const uint4*)&ghp[d0];
        pgL = *(const uint4*)&glp[d0];
    };
    auto sstore = [&](int buf) {
        *(uint4*)&LgH[buf][tr * 40 + c8] = pgH;
        *(uint4*)&LgL[buf][tr * 40 + c8] = pgL;
        const float xs[8] = {px0.x, px0.y, px0.z, px0.w, px1.x, px1.y, px1.z, px1.w};
        const float ys[8] = {py0.x, py0.y, py0.z, py0.w, py1.x, py1.y, py1.z, py1.w};
#pragma unroll
        for (int jj = 0; jj < 8; jj++) {
            int j = (jj + rot) & 7;            // lane-rotated: kills bank conflicts
            unsigned bx = __float_as_uint(xs[j]);
            unsigned by = __float_as_uint(ys[j]);
            unsigned hp = (bx >> 16) | (by & 0xffff0000u);
            float lx = xs[j] - __uint_as_float(bx & 0xffff0000u);
            float ly = ys[j] - __uint_as_float(by & 0xffff0000u);
            unsigned lp = (__float_as_uint(lx) >> 16) | (__float_as_uint(ly) & 0xffff0000u);
            LfH[buf][(nb + j) * 20 + dp] = hp;
            LfL[buf][(nb + j) * 20 + dp] = lp;
        }
    };
    auto scomp = [&](int buf) {
        bf16x8 aH[4], aL[4], bH[2], bL[2];
#pragma unroll
        for (int mt = 0; mt < 4; mt++) {
            aH[mt] = *(const bf16x8*)&LgH[buf][(mt * 16 + l16) * 40 + q * 8];
            aL[mt] = *(const bf16x8*)&LgL[buf][(mt * 16 + l16) * 40 + q * 8];
        }
#pragma unroll
        for (int nt = 0; nt < 2; nt++) {
            int nl = w * 32 + nt * 16 + l16;
            bH[nt] = *(const bf16x8*)&((const unsigned short*)LfH[buf])[nl * 40 + q * 8];
            bL[nt] = *(const bf16x8*)&((const unsigned short*)LfL[buf])[nl * 40 + q * 8];
        }
#pragma unroll
        for (int mt = 0; mt < 4; mt++)
#pragma unroll
            for (int nt = 0; nt < 2; nt++) {
                acc[mt][nt] = __builtin_amdgcn_mfma_f32_16x16x32_bf16(aH[mt], bH[nt], acc[mt][nt], 0, 0, 0);
                acc[mt][nt] = __builtin_amdgcn_mfma_f32_16x16x32_bf16(aH[mt], bL[nt], acc[mt][nt], 0, 0, 0);
                acc[mt][nt] = __builtin_amdgcn_mfma_f32_16x16x32_bf16(aL[mt], bH[nt], acc[mt][nt], 0, 0, 0);
            }
    };

    sload(0);
    sstore(0);
    __syncthreads();
    int cur = 0;
    for (int d0 = 0; d0 < DF_ - 32; d0 += 32) {
        sload(d0 + 32);        // issue next-tile loads (consumed below, before barrier)
        scomp(cur);            // MFMA on current buffer hides the load latency
        sstore(cur ^ 1);       // vmcnt wait lands here, after the MFMAs
        __syncthreads();
        cur ^= 1;
    }
    scomp(cur);                // last tile: no barrier needed

    float* sb = s + (size_t)b * T_ * N_;
#pragma unroll
    for (int mt = 0; mt < 4; mt++)
#pragma unroll
        for (int nt = 0; nt < 2; nt++)
#pragma unroll
            for (int r = 0; r < 4; r++) {
                int t = mt * 16 + q * 4 + r;
                int n = nblk + w * 32 + nt * 16 + l16;
                sb[(size_t)t * N_ + n] = acc[mt][nt][r];
            }
}

// ---------------------------------------------------------------------------
// softmax over n -> bf16 alpha.  One wave per row: no LDS, no barriers.
// ---------------------------------------------------------------------------
__global__ __launch_bounds__(256) void softmax_k(const float* __restrict__ s,
                                                 unsigned short* __restrict__ alpha,
                                                 const float* __restrict__ gptr) {
    const float g = gptr[0];
    const int row_id = blockIdx.x * 4 + (threadIdx.x >> 6);
    const int lane = threadIdx.x & 63;
    const float* row = s + (size_t)row_id * N_;
    unsigned short* arow = alpha + (size_t)row_id * N_;

    float4 x[4];
#pragma unroll
    for (int i = 0; i < 4; i++) {
        x[i] = *(const float4*)(row + i * 256 + lane * 4);   // perfectly coalesced
        x[i].x *= g; x[i].y *= g; x[i].z *= g; x[i].w *= g;
    }
    float m = x[0].x;
#pragma unroll
    for (int i = 0; i < 4; i++)
        m = fmaxf(m, fmaxf(fmaxf(x[i].x, x[i].y), fmaxf(x[i].z, x[i].w)));
#pragma unroll
    for (int off = 32; off > 0; off >>= 1) m = fmaxf(m, __shfl_xor(m, off, 64));

    float ev[16];
    float sum = 0.f;
#pragma unroll
    for (int i = 0; i < 4; i++) {
        ev[i * 4 + 0] = __expf(x[i].x - m);
        ev[i * 4 + 1] = __expf(x[i].y - m);
        ev[i * 4 + 2] = __expf(x[i].z - m);
        ev[i * 4 + 3] = __expf(x[i].w - m);
        sum += ev[i * 4 + 0] + ev[i * 4 + 1] + ev[i * 4 + 2] + ev[i * 4 + 3];
    }
#pragma unroll
    for (int off = 32; off > 0; off >>= 1) sum += __shfl_xor(sum, off, 64);
    float inv = 1.f / sum;
#pragma unroll
    for (int i = 0; i < 4; i++) {
        unsigned p0 = (unsigned)bf_rne(ev[i * 4 + 0] * inv) | ((unsigned)bf_rne(ev[i * 4 + 1] * inv) << 16);
        unsigned p1 = (unsigned)bf_rne(ev[i * 4 + 2] * inv) | ((unsigned)bf_rne(ev[i * 4 + 3] * inv) << 16);
        uint2 o; o.x = p0; o.y = p1;
        *(uint2*)&arow[i * 256 + lane * 4] = o;
    }
}

// ---------------------------------------------------------------------------
// gemm_h: hT[t][d] = sum_n f[d][n]*alpha[t][n]   (plain bf16)
// grid (DF/64, B) = 768 blocks, tile [64d x 64t], BK=64.
// Round-2 dbuf one-barrier form, (256,2).
// ---------------------------------------------------------------------------
__global__ __launch_bounds__(256, 2) void gemm_h(const float* __restrict__ f,
                                                 const unsigned short* __restrict__ alpha,
                                                 unsigned short* __restrict__ hT) {
    __shared__ unsigned short Lf[2][64 * 72];
    __shared__ unsigned short La[2][64 * 72];
    const int dblk = blockIdx.x * 64;
    const int b = blockIdx.y;
    const int tid = threadIdx.x;
    const int lane = tid & 63, w = tid >> 6, q = lane >> 4, l16 = lane & 15;

    const float* fb = f + (size_t)b * DF_ * N_;
    const unsigned short* ab = alpha + (size_t)b * T_ * N_;

    f32x4 acc[4];
#pragma unroll
    for (int i = 0; i < 4; i++) acc[i] = (f32x4)(0.f);

    const int fr_ = tid >> 2, fc = tid & 3;
    const float* frbase = fb + (size_t)(dblk + fr_) * N_ + fc * 16;
    const unsigned short* abase = ab + (size_t)fr_ * N_ + fc * 16;

    float4 pf0, pf1, pf2, pf3;
    uint4 pa0, pa1;

    auto hload = [&](int n0) {
        const float* fp = frbase + n0;
        pf0 = *(const float4*)&fp[0];
        pf1 = *(const float4*)&fp[4];
        pf2 = *(const float4*)&fp[8];
        pf3 = *(const float4*)&fp[12];
        pa0 = *(const uint4*)&abase[n0];
        pa1 = *(const uint4*)&abase[n0 + 8];
    };
    auto hstore = [&](int buf) {
        const float4 fx[4] = {pf0, pf1, pf2, pf3};
#pragma unroll
        for (int i = 0; i < 4; i++) {
            float4 x = fx[i];
            unsigned p0 = (unsigned)bf_rne(x.x) | ((unsigned)bf_rne(x.y) << 16);
            unsigned p1 = (unsigned)bf_rne(x.z) | ((unsigned)bf_rne(x.w) << 16);
            uint2 o; o.x = p0; o.y = p1;
            *(uint2*)&Lf[buf][fr_ * 72 + fc * 16 + i * 4] = o;
        }
        *(uint4*)&La[buf][fr_ * 72 + fc * 16]     = pa0;
        *(uint4*)&La[buf][fr_ * 72 + fc * 16 + 8] = pa1;
    };
    auto hcomp = [&](int buf) {
        bf16x8 af[2], bb[4][2];
#pragma unroll
        for (int kk = 0; kk < 2; kk++)
            af[kk] = *(const bf16x8*)&Lf[buf][(w * 16 + l16) * 72 + kk * 32 + q * 8];
#pragma unroll
        for (int nt = 0; nt < 4; nt++)
#pragma unroll
            for (int kk = 0; kk < 2; kk++)
                bb[nt][kk] = *(const bf16x8*)&La[buf][(nt * 16 + l16) * 72 + kk * 32 + q * 8];
#pragma unroll
        for (int nt = 0; nt < 4; nt++)
#pragma unroll
            for (int kk = 0; kk < 2; kk++)
                acc[nt] = __builtin_amdgcn_mfma_f32_16x16x32_bf16(af[kk], bb[nt][kk], acc[nt], 0, 0, 0);
    };

    hload(0);
    hstore(0);
    __syncthreads();
    int cur = 0;
    for (int n0 = 0; n0 < N_ - 64; n0 += 64) {
        hload(n0 + 64);        // issue next-tile loads
        hcomp(cur);            // compute current buffer
        hstore(cur ^ 1);       // consume loads after MFMAs
        __syncthreads();
        cur ^= 1;
    }
    hcomp(cur);

    unsigned short* hb = hT + (size_t)b * T_ * DF_;
#pragma unroll
    for (int nt = 0; nt < 4; nt++)
#pragma unroll
        for (int r = 0; r < 4; r++) {
            int d = dblk + w * 16 + q * 4 + r;
            int t = nt * 16 + l16;
            hb[(size_t)t * DF_ + d] = bf_rne(acc[nt][r]);
        }
}

// ---------------------------------------------------------------------------
// gemm_c: c[k][t] = sum_d W[d][k]*h[d][t] + bias[k]   (plain bf16)
// grid (K/64, B) = 256 blocks (1 block/CU), tile [64k x 64t], BK=64.
// Dbuf one-barrier: with 1 block/CU the pipeline is the only latency hiding.
// ---------------------------------------------------------------------------
__global__ __launch_bounds__(256, 2) void gemm_c(const unsigned short* __restrict__ WT_hi,
                                                 const unsigned short* __restrict__ hT,
                                                 const float* __restrict__ bias,
                                                 float* __restrict__ c) {
    __shared__ unsigned short LW[2][64 * 72];
    __shared__ unsigned short Lh[2][64 * 72];
    const int kblk = blockIdx.x * 64;
    const int b = blockIdx.y;
    const int tid = threadIdx.x;
    const int lane = tid & 63, w = tid >> 6, q = lane >> 4, l16 = lane & 15;

    const unsigned short* hb = hT + (size_t)b * T_ * DF_;

    f32x4 acc[4];
#pragma unroll
    for (int i = 0; i < 4; i++) acc[i] = (f32x4)(0.f);

    const int r_ = tid >> 2, cc = (tid & 3) * 16;
    const unsigned short* wbase = WT_hi + (size_t)(kblk + r_) * DF_ + cc;
    const unsigned short* hbase = hb + (size_t)r_ * DF_ + cc;

    uint4 pw0, pw1, ph0, ph1;
    auto cload = [&](int d0) {
        pw0 = *(const uint4*)&wbase[d0];
        pw1 = *(const uint4*)&wbase[d0 + 8];
        ph0 = *(const uint4*)&hbase[d0];
        ph1 = *(const uint4*)&hbase[d0 + 8];
    };
    auto cstore = [&](int buf) {
        *(uint4*)&LW[buf][r_ * 72 + cc]     = pw0;
        *(uint4*)&LW[buf][r_ * 72 + cc + 8] = pw1;
        *(uint4*)&Lh[buf][r_ * 72 + cc]     = ph0;
        *(uint4*)&Lh[buf][r_ * 72 + cc + 8] = ph1;
    };
    auto ccomp = [&](int buf) {
        bf16x8 aw[2], bh[4][2];
#pragma unroll
        for (int kk = 0; kk < 2; kk++)
            aw[kk] = *(const bf16x8*)&LW[buf][(w * 16 + l16) * 72 + kk * 32 + q * 8];
#pragma unroll
        for (int nt = 0; nt < 4; nt++)
#pragma unroll
            for (int kk = 0; kk < 2; kk++)
                bh[nt][kk] = *(const bf16x8*)&Lh[buf][(nt * 16 + l16) * 72 + kk * 32 + q * 8];
#pragma unroll
        for (int nt = 0; nt < 4; nt++)
#pragma unroll
            for (int kk = 0; kk < 2; kk++)
                acc[nt] = __builtin_amdgcn_mfma_f32_16x16x32_bf16(aw[kk], bh[nt][kk], acc[nt], 0, 0, 0);
    };

    cload(0);
    cstore(0);
    __syncthreads();
    int cur = 0;
    for (int d0 = 0; d0 < DF_ - 64; d0 += 64) {
        cload(d0 + 64);
        ccomp(cur);
        cstore(cur ^ 1);
        __syncthreads();
        cur ^= 1;
    }
    ccomp(cur);

    float* cb = c + (size_t)b * K_ * T_;
#pragma unroll
    for (int nt = 0; nt < 4; nt++)
#pragma unroll
        for (int r = 0; r < 4; r++) {
            int k = kblk + w * 16 + q * 4 + r;
            int t = nt * 16 + l16;
            cb[(size_t)k * T_ + t] = acc[nt][r] + bias[k];
        }
}

// ---------------------------------------------------------------------------
// cos_k: cos[b,i,j] = <c[:,i], e[:,j]> / (|c[:,i]| |e[:,j]|)
// ---------------------------------------------------------------------------
__global__ __launch_bounds__(256) void cos_k(const float* __restrict__ c,
                                             const float* __restrict__ e,
                                             float* __restrict__ out) {
    const int iq = threadIdx.x >> 6;
    const int i = blockIdx.x * 4 + iq;
    const int b = blockIdx.y;
    const int j = threadIdx.x & 63;
    const float* cb = c + (size_t)b * K_ * T_;
    const float* eb = e + (size_t)b * K_ * T_;

    float dot = 0.f, se = 0.f, sc = 0.f;
#pragma unroll 8
    for (int k = 0; k < K_; k++) {
        float cv = cb[(size_t)k * T_ + i];
        float ev = eb[(size_t)k * T_ + j];
        dot += cv * ev;
        se  += ev * ev;
        sc  += cv * cv;
    }
    out[((size_t)b * T_ + i) * T_ + j] = dot * rsqrtf(sc * se);
}

// ---------------------------------------------------------------------------
extern "C" void kernel_launch(void* const* d_in, const int* in_sizes, int n_in,
                              void* d_out, int out_size, void* d_ws, size_t ws_size,
                              hipStream_t stream) {
    const float* e     = (const float*)d_in[0];  // [B,K,T]
    const float* f     = (const float*)d_in[1];  // [B,DF,N]
    const float* gamma = (const float*)d_in[2];
    const float* W     = (const float*)d_in[3];  // [DF,K]
    const float* bias  = (const float*)d_in[4];  // [K]
    float* out = (float*)d_out;                  // [B,T,T]

    char* p = (char*)d_ws;
    unsigned short* W_hi  = (unsigned short*)p; p += (size_t)DF_ * K_ * 2;
    unsigned short* W_lo  = (unsigned short*)p; p += (size_t)DF_ * K_ * 2;
    unsigned short* WT_hi = (unsigned short*)p; p += (size_t)DF_ * K_ * 2;
    unsigned short* eT_hi = (unsigned short*)p; p += (size_t)B_ * T_ * K_ * 2;
    unsigned short* eT_lo = (unsigned short*)p; p += (size_t)B_ * T_ * K_ * 2;
    unsigned short* gT_hi = (unsigned short*)p; p += (size_t)B_ * T_ * DF_ * 2;
    unsigned short* gT_lo = (unsigned short*)p; p += (size_t)B_ * T_ * DF_ * 2;
    float*          s     = (float*)p;          p += (size_t)B_ * T_ * N_ * 4;
    unsigned short* alpha = (unsigned short*)p; p += (size_t)B_ * T_ * N_ * 2;
    unsigned short* hT    = (unsigned short*)p; p += (size_t)B_ * T_ * DF_ * 2;
    float*          c     = (float*)p;          p += (size_t)B_ * K_ * T_ * 4;

    prep_we <<<dim3(DF_ + 256),      256, 0, stream>>>(W, e, W_hi, W_lo, WT_hi, eT_hi, eT_lo);
    gemm_g  <<<dim3(DF_ / 64, B_),   256, 0, stream>>>(eT_hi, eT_lo, W_hi, W_lo, gT_hi, gT_lo);
    gemm_s  <<<dim3(512),            256, 0, stream>>>(gT_hi, gT_lo, f, s);
    softmax_k<<<dim3(B_ * T_ / 4),   256, 0, stream>>>(s, alpha, gamma);
    gemm_h  <<<dim3(DF_ / 64, B_),   256, 0, stream>>>(f, alpha, hT);
    gemm_c  <<<dim3(K_ / 64, B_),    256, 0, stream>>>(WT_hi, hT, bias, c);
    cos_k   <<<dim3(T_ / 4, B_),     256, 0, stream>>>(c, e, out);
}

// Round 7
// 374.896 us; speedup vs baseline: 1.0396x; 1.0060x over previous
//
#include <hip/hip_runtime.h>

#define B_  64
#define K_  256
#define T_  64
#define DF_ 768
#define N_  1024

typedef __attribute__((ext_vector_type(8))) short bf16x8;
typedef __attribute__((ext_vector_type(4))) float f32x4;

__device__ __forceinline__ unsigned short bf_rne(float x) {
    unsigned u = __float_as_uint(x);
    unsigned r = u + 0x7fffu + ((u >> 16) & 1u);
    return (unsigned short)(r >> 16);
}

// ---------------------------------------------------------------------------
// prep_we: blocks [0,768): W[d][k] -> W_hi/W_lo [d][k], WT_hi [k][d]
//          blocks [768,1024): e[b][k][t] -> eT_hi/eT_lo [b][t][k]
// ---------------------------------------------------------------------------
__global__ __launch_bounds__(256) void prep_we(const float* __restrict__ W,
                                               const float* __restrict__ e,
                                               unsigned short* __restrict__ W_hi,
                                               unsigned short* __restrict__ W_lo,
                                               unsigned short* __restrict__ WT_hi,
                                               unsigned short* __restrict__ eT_hi,
                                               unsigned short* __restrict__ eT_lo) {
    int blk = blockIdx.x;
    if (blk < DF_) {
        int d = blk, k = threadIdx.x;
        float w = W[d * K_ + k];
        unsigned u = __float_as_uint(w);
        unsigned short hs = (unsigned short)(u >> 16);  // truncation: exact hi
        float hi = __uint_as_float(u & 0xffff0000u);
        W_hi[d * K_ + k]   = hs;
        W_lo[d * K_ + k]   = bf_rne(w - hi);
        WT_hi[k * DF_ + d] = hs;
    } else {
        int q = blk - DF_;            // [0,256)
        int b = q >> 2, kq = q & 3;
        int t = threadIdx.x & 63, ko = threadIdx.x >> 6;
        const float* eb = e + (size_t)b * K_ * T_;
        unsigned short* eh = eT_hi + (size_t)b * T_ * K_;
        unsigned short* el = eT_lo + (size_t)b * T_ * K_;
#pragma unroll
        for (int i = 0; i < 16; i++) {
            int k = kq * 64 + ko * 16 + i;
            float x = eb[k * T_ + t];            // coalesced over t
            unsigned u = __float_as_uint(x);
            unsigned short hs = (unsigned short)(u >> 16);
            float hi = __uint_as_float(u & 0xffff0000u);
            eh[t * K_ + k] = hs;
            el[t * K_ + k] = bf_rne(x - hi);
        }
    }
}

// ---------------------------------------------------------------------------
// gemm_g: gT[t][d] = sum_k e[k][t]*W[d][k]   (split-bf16, 3-pass MFMA)
// grid (DF/64, B) = 768 blocks, tile [64t x 64d], BK=32.  Dbuf one-barrier.
// ---------------------------------------------------------------------------
__global__ __launch_bounds__(256, 2) void gemm_g(const unsigned short* __restrict__ eT_hi,
                                                 const unsigned short* __restrict__ eT_lo,
                                                 const unsigned short* __restrict__ W_hi,
                                                 const unsigned short* __restrict__ W_lo,
                                                 unsigned short* __restrict__ gT_hi,
                                                 unsigned short* __restrict__ gT_lo) {
    __shared__ unsigned short LeH[2][64 * 40], LeL[2][64 * 40];
    __shared__ unsigned short LwH[2][64 * 40], LwL[2][64 * 40];
    const int dblk = blockIdx.x * 64;
    const int b = blockIdx.y;
    const int tid = threadIdx.x;
    const int lane = tid & 63, w = tid >> 6, q = lane >> 4, l16 = lane & 15;

    const unsigned short* eh = eT_hi + (size_t)b * T_ * K_;
    const unsigned short* el = eT_lo + (size_t)b * T_ * K_;

    f32x4 acc[4];
#pragma unroll
    for (int i = 0; i < 4; i++) acc[i] = (f32x4)(0.f);

    const int tr = tid >> 2, c8 = (tid & 3) * 8;
    const unsigned short* ehp = eh + (size_t)tr * K_ + c8;
    const unsigned short* elp = el + (size_t)tr * K_ + c8;
    const unsigned short* whp = W_hi + (size_t)(dblk + tr) * K_ + c8;
    const unsigned short* wlp = W_lo + (size_t)(dblk + tr) * K_ + c8;

    uint4 peH, peL, pwH, pwL;
    auto gload = [&](int k0) {
        peH = *(const uint4*)&ehp[k0];
        peL = *(const uint4*)&elp[k0];
        pwH = *(const uint4*)&whp[k0];
        pwL = *(const uint4*)&wlp[k0];
    };
    auto gstore = [&](int buf) {
        *(uint4*)&LeH[buf][tr * 40 + c8] = peH;
        *(uint4*)&LeL[buf][tr * 40 + c8] = peL;
        *(uint4*)&LwH[buf][tr * 40 + c8] = pwH;
        *(uint4*)&LwL[buf][tr * 40 + c8] = pwL;
    };
    auto gcomp = [&](int buf) {
        bf16x8 aH[4], aL[4], bH, bL;
#pragma unroll
        for (int mt = 0; mt < 4; mt++) {
            aH[mt] = *(const bf16x8*)&LeH[buf][(mt * 16 + l16) * 40 + q * 8];
            aL[mt] = *(const bf16x8*)&LeL[buf][(mt * 16 + l16) * 40 + q * 8];
        }
        int dl = w * 16 + l16;
        bH = *(const bf16x8*)&LwH[buf][dl * 40 + q * 8];
        bL = *(const bf16x8*)&LwL[buf][dl * 40 + q * 8];
#pragma unroll
        for (int mt = 0; mt < 4; mt++) {
            acc[mt] = __builtin_amdgcn_mfma_f32_16x16x32_bf16(aH[mt], bH, acc[mt], 0, 0, 0);
            acc[mt] = __builtin_amdgcn_mfma_f32_16x16x32_bf16(aH[mt], bL, acc[mt], 0, 0, 0);
            acc[mt] = __builtin_amdgcn_mfma_f32_16x16x32_bf16(aL[mt], bH, acc[mt], 0, 0, 0);
        }
    };

    gload(0);
    gstore(0);
    __syncthreads();
    int cur = 0;
    for (int k0 = 0; k0 < K_ - 32; k0 += 32) {
        gload(k0 + 32);
        gcomp(cur);
        gstore(cur ^ 1);
        __syncthreads();
        cur ^= 1;
    }
    gcomp(cur);

    unsigned short* gh = gT_hi + (size_t)b * T_ * DF_;
    unsigned short* gl = gT_lo + (size_t)b * T_ * DF_;
#pragma unroll
    for (int mt = 0; mt < 4; mt++)
#pragma unroll
        for (int r = 0; r < 4; r++) {
            float x = acc[mt][r];
            int t = mt * 16 + q * 4 + r;
            int d = dblk + w * 16 + l16;
            unsigned u = __float_as_uint(x);
            unsigned short hs = (unsigned short)(u >> 16);
            float hi = __uint_as_float(u & 0xffff0000u);
            gh[t * DF_ + d] = hs;
            gl[t * DF_ + d] = bf_rne(x - hi);
        }
}

// ---------------------------------------------------------------------------
// gemm_s: s[t][n] = gamma * sum_d g[d][t]*f[d][n]   (split-bf16, 3-pass)
// 512 blocks (XCD-swizzled), tile [64t x 128n], BK=32, 2 blocks/CU, dbuf.
// Writes gamma-scaled s, and a per-block partial-softmax epilogue:
// for each of its 64 rows, (row-max m_blk, sum exp(x - m_blk)) over its 128
// columns -> mz[b][t][blk].  LDS is reused (pool) for the rescan.
// ---------------------------------------------------------------------------
__global__ __launch_bounds__(256, 2) void gemm_s(const unsigned short* __restrict__ gT_hi,
                                                 const unsigned short* __restrict__ gT_lo,
                                                 const float* __restrict__ f,
                                                 float* __restrict__ s,
                                                 float2* __restrict__ mz,
                                                 const float* __restrict__ gptr) {
    __shared__ __align__(16) char lds_pool[61440];
    unsigned short* LgH = (unsigned short*)(lds_pool);          // 2 x 2560 ushort
    unsigned short* LgL = (unsigned short*)(lds_pool + 10240);  // 2 x 2560 ushort
    unsigned*       LfH = (unsigned*)(lds_pool + 20480);        // 2 x 2560 uint
    unsigned*       LfL = (unsigned*)(lds_pool + 40960);        // 2 x 2560 uint

    const int flat = blockIdx.x;                  // 512 blocks
    const int b    = (flat & 7) * 8 + ((flat >> 3) & 7);
    const int blkid = flat >> 6;                  // n-block 0..7
    const int nblk = blkid * 128;
    const int tid = threadIdx.x;
    const int lane = tid & 63, w = tid >> 6, q = lane >> 4, l16 = lane & 15;

    const float gscale = gptr[0];

    const unsigned short* gh = gT_hi + (size_t)b * T_ * DF_;
    const unsigned short* gl = gT_lo + (size_t)b * T_ * DF_;

    f32x4 acc[4][2];
#pragma unroll
    for (int i = 0; i < 4; i++)
#pragma unroll
        for (int j = 0; j < 2; j++) acc[i][j] = (f32x4)(0.f);

    const int dp  = tid >> 4;          // d-pair 0..15
    const int nb  = (tid & 15) * 8;    // 8 consecutive n per thread
    const int rot = tid & 7;
    const int tr = tid >> 2, c8 = (tid & 3) * 8;

    const float* fbase = f + ((size_t)b * DF_ + dp * 2) * N_ + nblk + nb;
    const unsigned short* ghp = gh + (size_t)tr * DF_ + c8;
    const unsigned short* glp = gl + (size_t)tr * DF_ + c8;

    float4 px0, px1, py0, py1;
    uint4 pgH, pgL;

    auto sload = [&](int d0) {
        const float* fp = fbase + (size_t)d0 * N_;
        px0 = *(const float4*)&fp[0];
        px1 = *(const float4*)&fp[4];
        py0 = *(const float4*)&fp[N_ + 0];
        py1 = *(const float4*)&fp[N_ + 4];
        pgH = *(const uint4*)&ghp[d0];
        pgL = *(const uint4*)&glp[d0];
    };
    auto sstore = [&](int buf) {
        *(uint4*)&LgH[buf * 2560 + tr * 40 + c8] = pgH;
        *(uint4*)&LgL[buf * 2560 + tr * 40 + c8] = pgL;
        const float xs[8] = {px0.x, px0.y, px0.z, px0.w, px1.x, px1.y, px1.z, px1.w};
        const float ys[8] = {py0.x, py0.y, py0.z, py0.w, py1.x, py1.y, py1.z, py1.w};
#pragma unroll
        for (int jj = 0; jj < 8; jj++) {
            int j = (jj + rot) & 7;            // lane-rotated: kills bank conflicts
            unsigned bx = __float_as_uint(xs[j]);
            unsigned by = __float_as_uint(ys[j]);
            unsigned hp = (bx >> 16) | (by & 0xffff0000u);
            float lx = xs[j] - __uint_as_float(bx & 0xffff0000u);
            float ly = ys[j] - __uint_as_float(by & 0xffff0000u);
            unsigned lp = (__float_as_uint(lx) >> 16) | (__float_as_uint(ly) & 0xffff0000u);
            LfH[buf * 2560 + (nb + j) * 20 + dp] = hp;
            LfL[buf * 2560 + (nb + j) * 20 + dp] = lp;
        }
    };
    auto scomp = [&](int buf) {
        bf16x8 aH[4], aL[4], bH[2], bL[2];
#pragma unroll
        for (int mt = 0; mt < 4; mt++) {
            aH[mt] = *(const bf16x8*)&LgH[buf * 2560 + (mt * 16 + l16) * 40 + q * 8];
            aL[mt] = *(const bf16x8*)&LgL[buf * 2560 + (mt * 16 + l16) * 40 + q * 8];
        }
#pragma unroll
        for (int nt = 0; nt < 2; nt++) {
            int nl = w * 32 + nt * 16 + l16;
            bH[nt] = *(const bf16x8*)&((const unsigned short*)(LfH + buf * 2560))[nl * 40 + q * 8];
            bL[nt] = *(const bf16x8*)&((const unsigned short*)(LfL + buf * 2560))[nl * 40 + q * 8];
        }
#pragma unroll
        for (int mt = 0; mt < 4; mt++)
#pragma unroll
            for (int nt = 0; nt < 2; nt++) {
                acc[mt][nt] = __builtin_amdgcn_mfma_f32_16x16x32_bf16(aH[mt], bH[nt], acc[mt][nt], 0, 0, 0);
                acc[mt][nt] = __builtin_amdgcn_mfma_f32_16x16x32_bf16(aH[mt], bL[nt], acc[mt][nt], 0, 0, 0);
                acc[mt][nt] = __builtin_amdgcn_mfma_f32_16x16x32_bf16(aL[mt], bH[nt], acc[mt][nt], 0, 0, 0);
            }
    };

    sload(0);
    sstore(0);
    __syncthreads();
    int cur = 0;
    for (int d0 = 0; d0 < DF_ - 32; d0 += 32) {
        sload(d0 + 32);        // issue next-tile loads (consumed below, before barrier)
        scomp(cur);            // MFMA on current buffer hides the load latency
        sstore(cur ^ 1);       // vmcnt wait lands here, after the MFMAs
        __syncthreads();
        cur ^= 1;
    }
    scomp(cur);                // last tile

    // ---- epilogue: write gamma*s + partial softmax stats ----
    float* sb = s + (size_t)b * T_ * N_;
    float* Ls = (float*)lds_pool;          // 64 x 132 f32 = 33792 B (reuses pool)
    __syncthreads();                        // all LDS reads of scomp are done
#pragma unroll
    for (int mt = 0; mt < 4; mt++)
#pragma unroll
        for (int nt = 0; nt < 2; nt++)
#pragma unroll
            for (int r = 0; r < 4; r++) {
                int t = mt * 16 + q * 4 + r;
                int nl = w * 32 + nt * 16 + l16;
                float x = gscale * acc[mt][nt][r];
                sb[(size_t)t * N_ + nblk + nl] = x;
                Ls[t * 132 + nl] = x;
            }
    __syncthreads();
    {
        int t = tid >> 2, n0s = (tid & 3) * 32;
        float vb[32];
        float m = -3.4e38f;
#pragma unroll
        for (int jj = 0; jj < 8; jj++) {
            float4 v4 = *(const float4*)&Ls[t * 132 + n0s + jj * 4];
            vb[jj * 4 + 0] = v4.x; vb[jj * 4 + 1] = v4.y;
            vb[jj * 4 + 2] = v4.z; vb[jj * 4 + 3] = v4.w;
            m = fmaxf(m, fmaxf(fmaxf(v4.x, v4.y), fmaxf(v4.z, v4.w)));
        }
        float z = 0.f;
#pragma unroll
        for (int j2 = 0; j2 < 32; j2++) z += __expf(vb[j2] - m);
        float om = m;
        m = fmaxf(m, __shfl_xor(m, 1, 64));
        m = fmaxf(m, __shfl_xor(m, 2, 64));
        z *= __expf(om - m);
        z += __shfl_xor(z, 1, 64);
        z += __shfl_xor(z, 2, 64);
        if ((tid & 3) == 0)
            mz[((size_t)b * T_ + t) * 8 + blkid] = make_float2(m, z);
    }
}

// ---------------------------------------------------------------------------
// gemm_h: hT[t][d] = sum_n f[d][n]*alpha[t][n], alpha computed ON THE FLY
// from gamma-scaled s + per-block partial stats mz.  grid (DF/64, B),
// tile [64d x 64t], BK=64, dbuf one-barrier.
// ---------------------------------------------------------------------------
__global__ __launch_bounds__(256, 2) void gemm_h(const float* __restrict__ f,
                                                 const float* __restrict__ s,
                                                 const float2* __restrict__ mz,
                                                 unsigned short* __restrict__ hT) {
    __shared__ unsigned short Lf[2][64 * 72];
    __shared__ unsigned short La[2][64 * 72];
    __shared__ float sM[64], sI[64];
    const int dblk = blockIdx.x * 64;
    const int b = blockIdx.y;
    const int tid = threadIdx.x;
    const int lane = tid & 63, w = tid >> 6, q = lane >> 4, l16 = lane & 15;

    const float* fb = f + (size_t)b * DF_ * N_;

    f32x4 acc[4];
#pragma unroll
    for (int i = 0; i < 4; i++) acc[i] = (f32x4)(0.f);

    // combine partial softmax stats: M = max over 8 blocks; Z rescaled-sum
    if (tid < 64) {
        const float2* mzp = mz + ((size_t)b * T_ + tid) * 8;
        float2 p0 = mzp[0], p1 = mzp[1], p2 = mzp[2], p3 = mzp[3];
        float2 p4 = mzp[4], p5 = mzp[5], p6 = mzp[6], p7 = mzp[7];
        float M = fmaxf(fmaxf(fmaxf(p0.x, p1.x), fmaxf(p2.x, p3.x)),
                        fmaxf(fmaxf(p4.x, p5.x), fmaxf(p6.x, p7.x)));
        float Z = p0.y * __expf(p0.x - M) + p1.y * __expf(p1.x - M) +
                  p2.y * __expf(p2.x - M) + p3.y * __expf(p3.x - M) +
                  p4.y * __expf(p4.x - M) + p5.y * __expf(p5.x - M) +
                  p6.y * __expf(p6.x - M) + p7.y * __expf(p7.x - M);
        sM[tid] = M;
        sI[tid] = 1.f / Z;
    }

    const int fr_ = tid >> 2, fc = tid & 3;
    const float* frbase = fb + (size_t)(dblk + fr_) * N_ + fc * 16;
    const float* srbase = s + ((size_t)b * T_ + fr_) * N_ + fc * 16;

    float4 pf0, pf1, pf2, pf3;
    float4 ps0, ps1, ps2, ps3;

    auto hload = [&](int n0) {
        const float* fp = frbase + n0;
        pf0 = *(const float4*)&fp[0];
        pf1 = *(const float4*)&fp[4];
        pf2 = *(const float4*)&fp[8];
        pf3 = *(const float4*)&fp[12];
        const float* sp = srbase + n0;
        ps0 = *(const float4*)&sp[0];
        ps1 = *(const float4*)&sp[4];
        ps2 = *(const float4*)&sp[8];
        ps3 = *(const float4*)&sp[12];
    };

    hload(0);
    __syncthreads();                 // sM/sI visible
    const float rowM = sM[fr_], rowI = sI[fr_];

    auto hstore = [&](int buf) {
        const float4 fx[4] = {pf0, pf1, pf2, pf3};
        const float4 sx[4] = {ps0, ps1, ps2, ps3};
#pragma unroll
        for (int i = 0; i < 4; i++) {
            float4 x = fx[i];
            unsigned p0 = (unsigned)bf_rne(x.x) | ((unsigned)bf_rne(x.y) << 16);
            unsigned p1 = (unsigned)bf_rne(x.z) | ((unsigned)bf_rne(x.w) << 16);
            uint2 o; o.x = p0; o.y = p1;
            *(uint2*)&Lf[buf][fr_ * 72 + fc * 16 + i * 4] = o;

            float4 sv = sx[i];
            float a0 = __expf(sv.x - rowM) * rowI;
            float a1 = __expf(sv.y - rowM) * rowI;
            float a2 = __expf(sv.z - rowM) * rowI;
            float a3 = __expf(sv.w - rowM) * rowI;
            unsigned q0 = (unsigned)bf_rne(a0) | ((unsigned)bf_rne(a1) << 16);
            unsigned q1 = (unsigned)bf_rne(a2) | ((unsigned)bf_rne(a3) << 16);
            uint2 oa; oa.x = q0; oa.y = q1;
            *(uint2*)&La[buf][fr_ * 72 + fc * 16 + i * 4] = oa;
        }
    };
    auto hcomp = [&](int buf) {
        bf16x8 af[2], bb[4][2];
#pragma unroll
        for (int kk = 0; kk < 2; kk++)
            af[kk] = *(const bf16x8*)&Lf[buf][(w * 16 + l16) * 72 + kk * 32 + q * 8];
#pragma unroll
        for (int nt = 0; nt < 4; nt++)
#pragma unroll
            for (int kk = 0; kk < 2; kk++)
                bb[nt][kk] = *(const bf16x8*)&La[buf][(nt * 16 + l16) * 72 + kk * 32 + q * 8];
#pragma unroll
        for (int nt = 0; nt < 4; nt++)
#pragma unroll
            for (int kk = 0; kk < 2; kk++)
                acc[nt] = __builtin_amdgcn_mfma_f32_16x16x32_bf16(af[kk], bb[nt][kk], acc[nt], 0, 0, 0);
    };

    hstore(0);
    __syncthreads();
    int cur = 0;
    for (int n0 = 0; n0 < N_ - 64; n0 += 64) {
        hload(n0 + 64);        // issue next-tile loads
        hcomp(cur);            // compute current buffer
        hstore(cur ^ 1);       // consume loads after MFMAs
        __syncthreads();
        cur ^= 1;
    }
    hcomp(cur);

    unsigned short* hb = hT + (size_t)b * T_ * DF_;
#pragma unroll
    for (int nt = 0; nt < 4; nt++)
#pragma unroll
        for (int r = 0; r < 4; r++) {
            int d = dblk + w * 16 + q * 4 + r;
            int t = nt * 16 + l16;
            hb[(size_t)t * DF_ + d] = bf_rne(acc[nt][r]);
        }
}

// ---------------------------------------------------------------------------
// gemm_c: c[k][t] = sum_d W[d][k]*h[d][t] + bias[k]   (plain bf16)
// grid (K/64, B) = 256 blocks, tile [64k x 64t], BK=64, dbuf one-barrier.
// ---------------------------------------------------------------------------
__global__ __launch_bounds__(256, 2) void gemm_c(const unsigned short* __restrict__ WT_hi,
                                                 const unsigned short* __restrict__ hT,
                                                 const float* __restrict__ bias,
                                                 float* __restrict__ c) {
    __shared__ unsigned short LW[2][64 * 72];
    __shared__ unsigned short Lh[2][64 * 72];
    const int kblk = blockIdx.x * 64;
    const int b = blockIdx.y;
    const int tid = threadIdx.x;
    const int lane = tid & 63, w = tid >> 6, q = lane >> 4, l16 = lane & 15;

    const unsigned short* hb = hT + (size_t)b * T_ * DF_;

    f32x4 acc[4];
#pragma unroll
    for (int i = 0; i < 4; i++) acc[i] = (f32x4)(0.f);

    const int r_ = tid >> 2, cc = (tid & 3) * 16;
    const unsigned short* wbase = WT_hi + (size_t)(kblk + r_) * DF_ + cc;
    const unsigned short* hbase = hb + (size_t)r_ * DF_ + cc;

    uint4 pw0, pw1, ph0, ph1;
    auto cload = [&](int d0) {
        pw0 = *(const uint4*)&wbase[d0];
        pw1 = *(const uint4*)&wbase[d0 + 8];
        ph0 = *(const uint4*)&hbase[d0];
        ph1 = *(const uint4*)&hbase[d0 + 8];
    };
    auto cstore = [&](int buf) {
        *(uint4*)&LW[buf][r_ * 72 + cc]     = pw0;
        *(uint4*)&LW[buf][r_ * 72 + cc + 8] = pw1;
        *(uint4*)&Lh[buf][r_ * 72 + cc]     = ph0;
        *(uint4*)&Lh[buf][r_ * 72 + cc + 8] = ph1;
    };
    auto ccomp = [&](int buf) {
        bf16x8 aw[2], bh[4][2];
#pragma unroll
        for (int kk = 0; kk < 2; kk++)
            aw[kk] = *(const bf16x8*)&LW[buf][(w * 16 + l16) * 72 + kk * 32 + q * 8];
#pragma unroll
        for (int nt = 0; nt < 4; nt++)
#pragma unroll
            for (int kk = 0; kk < 2; kk++)
                bh[nt][kk] = *(const bf16x8*)&Lh[buf][(nt * 16 + l16) * 72 + kk * 32 + q * 8];
#pragma unroll
        for (int nt = 0; nt < 4; nt++)
#pragma unroll
            for (int kk = 0; kk < 2; kk++)
                acc[nt] = __builtin_amdgcn_mfma_f32_16x16x32_bf16(aw[kk], bh[nt][kk], acc[nt], 0, 0, 0);
    };

    cload(0);
    cstore(0);
    __syncthreads();
    int cur = 0;
    for (int d0 = 0; d0 < DF_ - 64; d0 += 64) {
        cload(d0 + 64);
        ccomp(cur);
        cstore(cur ^ 1);
        __syncthreads();
        cur ^= 1;
    }
    ccomp(cur);

    float* cb = c + (size_t)b * K_ * T_;
#pragma unroll
    for (int nt = 0; nt < 4; nt++)
#pragma unroll
        for (int r = 0; r < 4; r++) {
            int k = kblk + w * 16 + q * 4 + r;
            int t = nt * 16 + l16;
            cb[(size_t)k * T_ + t] = acc[nt][r] + bias[k];
        }
}

// ---------------------------------------------------------------------------
// cos_k: cos[b,i,j] = <c[:,i], e[:,j]> / (|c[:,i]| |e[:,j]|)
// ---------------------------------------------------------------------------
__global__ __launch_bounds__(256) void cos_k(const float* __restrict__ c,
                                             const float* __restrict__ e,
                                             float* __restrict__ out) {
    const int iq = threadIdx.x >> 6;
    const int i = blockIdx.x * 4 + iq;
    const int b = blockIdx.y;
    const int j = threadIdx.x & 63;
    const float* cb = c + (size_t)b * K_ * T_;
    const float* eb = e + (size_t)b * K_ * T_;

    float dot = 0.f, se = 0.f, sc = 0.f;
#pragma unroll 8
    for (int k = 0; k < K_; k++) {
        float cv = cb[(size_t)k * T_ + i];
        float ev = eb[(size_t)k * T_ + j];
        dot += cv * ev;
        se  += ev * ev;
        sc  += cv * cv;
    }
    out[((size_t)b * T_ + i) * T_ + j] = dot * rsqrtf(sc * se);
}

// ---------------------------------------------------------------------------
extern "C" void kernel_launch(void* const* d_in, const int* in_sizes, int n_in,
                              void* d_out, int out_size, void* d_ws, size_t ws_size,
                              hipStream_t stream) {
    const float* e     = (const float*)d_in[0];  // [B,K,T]
    const float* f     = (const float*)d_in[1];  // [B,DF,N]
    const float* gamma = (const float*)d_in[2];
    const float* W     = (const float*)d_in[3];  // [DF,K]
    const float* bias  = (const float*)d_in[4];  // [K]
    float* out = (float*)d_out;                  // [B,T,T]

    char* p = (char*)d_ws;
    unsigned short* W_hi  = (unsigned short*)p; p += (size_t)DF_ * K_ * 2;
    unsigned short* W_lo  = (unsigned short*)p; p += (size_t)DF_ * K_ * 2;
    unsigned short* WT_hi = (unsigned short*)p; p += (size_t)DF_ * K_ * 2;
    unsigned short* eT_hi = (unsigned short*)p; p += (size_t)B_ * T_ * K_ * 2;
    unsigned short* eT_lo = (unsigned short*)p; p += (size_t)B_ * T_ * K_ * 2;
    unsigned short* gT_hi = (unsigned short*)p; p += (size_t)B_ * T_ * DF_ * 2;
    unsigned short* gT_lo = (unsigned short*)p; p += (size_t)B_ * T_ * DF_ * 2;
    float*          s     = (float*)p;          p += (size_t)B_ * T_ * N_ * 4;
    float2*         mz    = (float2*)p;         p += (size_t)B_ * T_ * 8 * sizeof(float2);
    unsigned short* hT    = (unsigned short*)p; p += (size_t)B_ * T_ * DF_ * 2;
    float*          c     = (float*)p;          p += (size_t)B_ * K_ * T_ * 4;

    prep_we <<<dim3(DF_ + 256),      256, 0, stream>>>(W, e, W_hi, W_lo, WT_hi, eT_hi, eT_lo);
    gemm_g  <<<dim3(DF_ / 64, B_),   256, 0, stream>>>(eT_hi, eT_lo, W_hi, W_lo, gT_hi, gT_lo);
    gemm_s  <<<dim3(512),            256, 0, stream>>>(gT_hi, gT_lo, f, s, mz, gamma);
    gemm_h  <<<dim3(DF_ / 64, B_),   256, 0, stream>>>(f, s, mz, hT);
    gemm_c  <<<dim3(K_ / 64, B_),    256, 0, stream>>>(WT_hi, hT, bias, c);
    cos_k   <<<dim3(T_ / 4, B_),     256, 0, stream>>>(c, e, out);
}